// Round 5
// baseline (18713.673 us; speedup 1.0000x reference)
//
#include <hip/hip_runtime.h>
#include <math.h>

#define B_   128
#define T_   2048
#define DIN  128
#define H_   256

typedef float fx4 __attribute__((ext_vector_type(4)));

__device__ __forceinline__ void vfma(fx4& a, float s, fx4 w) {
  a.x = fmaf(s, w.x, a.x);
  a.y = fmaf(s, w.y, a.y);
  a.z = fmaf(s, w.z, a.z);
  a.w = fmaf(s, w.w, a.w);
}

__device__ __forceinline__ void f4fma(float4& a, float s, const float4& w) {
  a.x = fmaf(s, w.x, a.x);
  a.y = fmaf(s, w.y, a.y);
  a.z = fmaf(s, w.z, a.z);
  a.w = fmaf(s, w.w, a.w);
}

// ===================== phase 1: input projections =====================
// grid: (128*Tc/32, 3), block 256.  Computes xout[R][ct*256+h] for R=b*Tc+tau.
// Measured round 2: ~0.64 ms total at Tc=2048 (~81 TF) — not the bottleneck.
__global__ __launch_bounds__(256, 3) void proj_kernel(
    const float* __restrict__ x,
    const float* __restrict__ Wz, const float* __restrict__ Wr, const float* __restrict__ Wx,
    const float* __restrict__ Bz, const float* __restrict__ Br,
    float* __restrict__ xout, int t0, int Tc)
{
  __shared__ float xs[32 * DIN];    // 16 KB
  __shared__ float ws[32 * H_];     // 32 KB
  const int tid = threadIdx.x;
  const int c0  = tid & 63;
  const int rg  = tid >> 6;
  const int rt  = blockIdx.x;
  const int ct  = blockIdx.y;       // 0:Wz 1:Wr 2:Wx
  const float* Wm = (ct == 0) ? Wz : (ct == 1) ? Wr : Wx;

  const int R0   = rt * 32;
  const int bb   = R0 / Tc;
  const int tau0 = R0 - bb * Tc;
  const float* xsrc = x + ((size_t)bb * T_ + t0 + tau0) * DIN;

  #pragma unroll
  for (int u = 0; u < 4; ++u) {
    int id = tid + 256 * u;
    *(float4*)&xs[4 * id] = *(const float4*)&xsrc[4 * id];
  }

  float4 acc[8];
  #pragma unroll
  for (int r = 0; r < 8; ++r) acc[r] = make_float4(0.f, 0.f, 0.f, 0.f);

  for (int ks = 0; ks < DIN; ks += 32) {
    __syncthreads();
    #pragma unroll
    for (int u = 0; u < 8; ++u) {
      int id = tid + 256 * u;
      int row = id >> 6, col4 = id & 63;
      *(float4*)&ws[4 * id] = *(const float4*)&Wm[(size_t)(ks + row) * H_ + 4 * col4];
    }
    __syncthreads();
    #pragma unroll
    for (int kk = 0; kk < 32; kk += 4) {
      float4 xv[8];
      #pragma unroll
      for (int r = 0; r < 8; ++r)
        xv[r] = *(const float4*)&xs[(8 * rg + r) * DIN + ks + kk];
      #pragma unroll
      for (int u = 0; u < 4; ++u) {
        float4 wv = *(const float4*)&ws[(kk + u) * H_ + 4 * c0];
        #pragma unroll
        for (int r = 0; r < 8; ++r) {
          float s = (u == 0) ? xv[r].x : (u == 1) ? xv[r].y : (u == 2) ? xv[r].z : xv[r].w;
          f4fma(acc[r], s, wv);
        }
      }
    }
  }

  float4 bias = make_float4(0.f, 0.f, 0.f, 0.f);
  if (ct == 0)      bias = *(const float4*)&Bz[4 * c0];
  else if (ct == 1) bias = *(const float4*)&Br[4 * c0];

  #pragma unroll
  for (int r = 0; r < 8; ++r) {
    int R = R0 + 8 * rg + r;
    float4 v = acc[r];
    v.x += bias.x; v.y += bias.y; v.z += bias.z; v.w += bias.w;
    *(float4*)&xout[(size_t)R * 768 + ct * H_ + 4 * c0] = v;
  }
}

// ===================== phase 2: recurrent scan, split-H =====================
// 256 blocks = 2 per batch (blockIdx>>1 = batch, &1 = column half).
// Each block: 512 threads, owns 128 output cols; its full weight slice
// (3 x 256 x 128 = 384 KB) is VGPR-resident: 48 fx4/thread, asm-pinned so the
// compiler CANNOT rematerialize from L2 (round-2 failure: VGPR_Count=128
// proved remat; 650 KB/step streamed at the ~145 GB/s per-CU load ceiling
// -> 9.24 ms).  Pair exchanges 128-float h-halves per step via LLC
// (agent-scope atomics, double-buffered slots, monotonic flags; slot-overwrite
// race impossible: partner overwrites slot s at tau+1 only after observing our
// tau flag, published only after we consumed slot s).  The fetch runs on the
// first REMOTE k-group's lanes (kb==8 for half 0, kb==0 for half 1) so it
// starts immediately and overlaps the local waves' FMAs.  3 barriers/step.
__global__ __launch_bounds__(512, 2) void scan_kernel(
    const float* __restrict__ xproj,
    const float* __restrict__ Rz, const float* __restrict__ Rr,
    const float* __restrict__ Uh, const float* __restrict__ Bh,
    const float* __restrict__ h0,
    float* __restrict__ hcarry, float* __restrict__ out,
    float* __restrict__ comm, int* __restrict__ flags,
    int t0, int Tc)
{
  __shared__ fx4 pZ[512], pR[512], pU[512];   // 24 KB partials
  __shared__ float hbuf[2][H_];               // 2 KB, parity double-buffer

  const int tid  = threadIdx.x;
  const int b    = blockIdx.x >> 1;
  const int half = blockIdx.x & 1;
  const int g    = tid & 31;          // col group: 4 cols
  const int kb   = tid >> 5;          // k-chunk 0..15 (16 rows each)
  const int cbase = half * 128 + 4 * g;
  const bool kLocal = ((kb >> 3) == half);   // wave-uniform (kb=2w,2w+1)
  const bool fetcher = (kb == (half ? 0 : 8));   // first REMOTE k-group
  const int myid  = b * 2 + half;
  const int othid = b * 2 + (1 - half);

  const float* xp = xproj + (size_t)b * Tc * 768;
  float* outp = out + ((size_t)b * T_ + t0) * H_;

  // ---- resident weights: 48 fx4 = 192 VGPRs, pinned ----
  fx4 rz[16], rr[16], ru[16];
  #pragma unroll
  for (int i = 0; i < 16; ++i) {
    const size_t row = (size_t)(kb * 16 + i) * H_ + cbase;
    rz[i] = *(const fx4*)&Rz[row];
    rr[i] = *(const fx4*)&Rr[row];
    ru[i] = *(const fx4*)&Uh[row];
  }
  #pragma unroll
  for (int i = 0; i < 16; ++i) {
    asm volatile("" : "+v"(rz[i]));
    asm volatile("" : "+v"(rr[i]));
    asm volatile("" : "+v"(ru[i]));
  }

  float bh_j = 0.f;
  if (tid < 128) bh_j = Bh[half * 128 + tid];

  const float* hsrc = (t0 == 0) ? (h0 + (size_t)b * H_) : (hcarry + (size_t)b * H_);
  if (tid < 64) *(fx4*)&hbuf[0][4 * tid] = *(const fx4*)&hsrc[4 * tid];
  __syncthreads();

  int p = 0;   // input-h parity; publish slot for this step is also p
  #pragma unroll 1
  for (int tau = 0; tau < Tc; ++tau) {
    // x-proj loads for this step (consumed at epilogue; latency hides under FMAs)
    float xzv = 0.f, xrv = 0.f, xxv = 0.f;
    if (tid < 128) {
      const float* xt = xp + (size_t)tau * 768 + half * 128 + tid;
      xzv = xt[0]; xrv = xt[256]; xxv = xt[512];
    }

    fx4 az = {0.f, 0.f, 0.f, 0.f};
    fx4 ar = {0.f, 0.f, 0.f, 0.f};
    fx4 au = {0.f, 0.f, 0.f, 0.f};

    auto do_fmas = [&]() {
      #pragma unroll
      for (int u = 0; u < 4; ++u) {
        fx4 h4 = *(const fx4*)&hbuf[p][kb * 16 + 4 * u];
        vfma(az, h4.x, rz[4*u+0]); vfma(ar, h4.x, rr[4*u+0]); vfma(au, h4.x, ru[4*u+0]);
        vfma(az, h4.y, rz[4*u+1]); vfma(ar, h4.y, rr[4*u+1]); vfma(au, h4.y, ru[4*u+1]);
        vfma(az, h4.z, rz[4*u+2]); vfma(ar, h4.z, rr[4*u+2]); vfma(au, h4.z, ru[4*u+2]);
        vfma(az, h4.w, rz[4*u+3]); vfma(ar, h4.w, rr[4*u+3]); vfma(au, h4.w, ru[4*u+3]);
      }
      pZ[tid] = az; pR[tid] = ar; pU[tid] = au;
    };

    // local-half FMAs proceed without partner data
    if (kLocal) do_fmas();

    // fetch partner's h-half; runs on a remote wave so it starts at step top
    if (fetcher && tau > 0) {
      const int slot = p ^ 1;                   // partner published at its tau-1
      const int want = t0 + tau;                // monotonic; 0xAA poison is negative
      const int fidx = othid * 2 + slot;
      while (__hip_atomic_load(&flags[fidx], __ATOMIC_ACQUIRE, __HIP_MEMORY_SCOPE_AGENT) < want) { }
      const float* src = comm + (size_t)(othid * 2 + slot) * 128 + 4 * g;
      float v0 = __hip_atomic_load(&src[0], __ATOMIC_RELAXED, __HIP_MEMORY_SCOPE_AGENT);
      float v1 = __hip_atomic_load(&src[1], __ATOMIC_RELAXED, __HIP_MEMORY_SCOPE_AGENT);
      float v2 = __hip_atomic_load(&src[2], __ATOMIC_RELAXED, __HIP_MEMORY_SCOPE_AGENT);
      float v3 = __hip_atomic_load(&src[3], __ATOMIC_RELAXED, __HIP_MEMORY_SCOPE_AGENT);
      float* dst = &hbuf[p][(1 - half) * 128 + 4 * g];
      dst[0] = v0; dst[1] = v1; dst[2] = v2; dst[3] = v3;
    }
    __syncthreads();                            // B1: remote h visible

    if (!kLocal) do_fmas();
    __syncthreads();                            // B2: partials ready

    if (tid < 128) {
      const float* fZ = (const float*)pZ;
      const float* fR = (const float*)pR;
      const float* fU = (const float*)pU;
      float sz = xzv, sr = xrv, su = 0.f;
      #pragma unroll
      for (int q = 0; q < 16; ++q) {
        sz += fZ[q * 128 + tid];
        sr += fR[q * 128 + tid];
        su += fU[q * 128 + tid];
      }
      float zt = 1.f / (1.f + expf(-sz));
      float rt = 1.f / (1.f + expf(-sr));
      float zi = xxv + rt * su;
      float a  = fabsf(zi);
      float mr = (zi / a) * fmaxf(a + bh_j, 0.f);   // modReLU, faithful incl 0/0
      float hold = hbuf[p][half * 128 + tid];
      float hn = zt * hold + (1.f - zt) * mr;
      outp[(size_t)tau * H_ + half * 128 + tid] = hn;
      hbuf[p ^ 1][half * 128 + tid] = hn;
      __hip_atomic_store(&comm[(size_t)(myid * 2 + p) * 128 + tid], hn,
                         __ATOMIC_RELAXED, __HIP_MEMORY_SCOPE_AGENT);
    }
    __syncthreads();                            // B3: drains comm stores

    if (tid == 0)
      __hip_atomic_store(&flags[myid * 2 + p], t0 + tau + 1,
                         __ATOMIC_RELEASE, __HIP_MEMORY_SCOPE_AGENT);
    p ^= 1;
  }

  if (tid < 128) hcarry[(size_t)b * H_ + half * 128 + tid] = hbuf[0][half * 128 + tid];
}

// ===================== launcher =====================
extern "C" void kernel_launch(void* const* d_in, const int* in_sizes, int n_in,
                              void* d_out, int out_size, void* d_ws, size_t ws_size,
                              hipStream_t stream)
{
  const float* x  = (const float*)d_in[0];
  const float* h0 = (const float*)d_in[1];
  const float* Wz = (const float*)d_in[2];
  const float* Wr = (const float*)d_in[3];
  const float* Wx = (const float*)d_in[4];
  const float* Uh = (const float*)d_in[5];
  const float* Rz = (const float*)d_in[6];
  const float* Rr = (const float*)d_in[7];
  const float* Bz = (const float*)d_in[8];
  const float* Br = (const float*)d_in[9];
  const float* Bh = (const float*)d_in[10];
  float* out = (float*)d_out;

  // ws layout: [0,128K) hcarry | [128K,384K) comm | [384K,+2K) flags | [1M,...) xproj
  float* hcarry = (float*)d_ws;
  float* comm   = (float*)((char*)d_ws + 131072);
  int*   flags  = (int*)((char*)d_ws + 131072 + 262144);
  float* xproj  = (float*)((char*)d_ws + 1048576);

  // flags MUST be reset every launch: graph replay may run without re-poison,
  // and stale high flags would let readers race ahead of writers.
  hipMemsetAsync(flags, 0, 512 * sizeof(int), stream);

  // largest chunk of T that fits in workspace (round-2 bench proved
  // ws_size >= 806 MB, so Tc=2048 single-chunk is the expected path)
  int Tc = 32;
  const int cands[7] = {2048, 1024, 512, 256, 128, 64, 32};
  for (int i = 0; i < 7; ++i) {
    size_t need = 1048576 + (size_t)cands[i] * 128 * 768 * 4;
    if (need <= ws_size) { Tc = cands[i]; break; }
  }

  const int nch = T_ / Tc;
  for (int c = 0; c < nch; ++c) {
    int t0 = c * Tc;
    dim3 g1(128 * Tc / 32, 3);
    proj_kernel<<<g1, 256, 0, stream>>>(x, Wz, Wr, Wx, Bz, Br, xproj, t0, Tc);
    scan_kernel<<<256, 512, 0, stream>>>(xproj, Rz, Rr, Uh, Bh, h0,
                                         hcarry, out, comm, flags, t0, Tc);
  }
}